// Round 16
// baseline (419.664 us; speedup 1.0000x reference)
//
#include <hip/hip_runtime.h>
#include <hip/hip_bf16.h>
#include <math.h>

typedef __attribute__((ext_vector_type(8))) _Float16 f16x8;
typedef __attribute__((ext_vector_type(4))) _Float16 f16x4;
typedef __attribute__((ext_vector_type(4))) float f32x4;
typedef __attribute__((ext_vector_type(4), aligned(4))) float f32x4u;   // 4B-aligned vector load

#define AS1(p) ((const __attribute__((address_space(1))) void*)(p))
#define AS3(p) ((__attribute__((address_space(3))) void*)(p))

__device__ __forceinline__ float leaky02(float x){ return x > 0.f ? x : 0.2f*x; }
__device__ __forceinline__ ushort f2h(float f){ _Float16 h = (_Float16)f; return *(ushort*)&h; }
__device__ __forceinline__ float h2f(ushort u){ _Float16 h = *(_Float16*)&u; return (float)h; }

// ---------------- CSR build over dst ----------------
__global__ void count_kernel(const int* __restrict__ dst, int* __restrict__ cnt, int E){
  int e = blockIdx.x*blockDim.x + threadIdx.x;
  if (e < E) atomicAdd(&cnt[dst[e]], 1);
}

__global__ void scanA_kernel(const int* __restrict__ cnt, int* __restrict__ bsum, int N){
  __shared__ int sd[256];
  int i = blockIdx.x*256 + threadIdx.x;
  sd[threadIdx.x] = (i<N) ? cnt[i] : 0;
  __syncthreads();
  for (int off=128; off>0; off>>=1){
    if (threadIdx.x < off) sd[threadIdx.x] += sd[threadIdx.x+off];
    __syncthreads();
  }
  if (threadIdx.x==0) bsum[blockIdx.x] = sd[0];
}
__global__ void scanB_kernel(int* __restrict__ bsum, int B){
  __shared__ int sd[256];
  int t = threadIdx.x;
  int v = (t<B) ? bsum[t] : 0;
  sd[t] = v;
  __syncthreads();
  for (int off=1; off<256; off<<=1){
    int u = (t>=off) ? sd[t-off] : 0;
    __syncthreads();
    sd[t] += u;
    __syncthreads();
  }
  if (t<B) bsum[t] = sd[t] - v;   // exclusive
}
__global__ void scanC_kernel(const int* __restrict__ cnt, const int* __restrict__ bsum,
                             int* __restrict__ row_ptr, int N){
  __shared__ int sd[256];
  int i = blockIdx.x*256 + threadIdx.x;
  int v = (i<N) ? cnt[i] : 0;
  sd[threadIdx.x] = v;
  __syncthreads();
  for (int off=1; off<256; off<<=1){
    int u = (threadIdx.x>=off) ? sd[threadIdx.x-off] : 0;
    __syncthreads();
    sd[threadIdx.x] += u;
    __syncthreads();
  }
  if (i < N) row_ptr[i+1] = sd[threadIdx.x] + bsum[blockIdx.x];
  if (i == 0) row_ptr[0] = 0;
}

__global__ void scatter_kernel(const int* __restrict__ src, const int* __restrict__ dst,
                               const int* __restrict__ row_ptr, int* __restrict__ cursor,
                               int* __restrict__ epos, int* __restrict__ csr_src, int E){
  int e = blockIdx.x*blockDim.x + threadIdx.x;
  if (e < E){
    int d = dst[e];
    int pos = row_ptr[d] + atomicAdd(&cursor[d], 1);
    epos[e] = pos;
    csr_src[pos] = src[e];
  }
}

// ---------------- fp32 -> fp16 conversion, 4 segments in one launch ----------------
__global__ void conv4_kernel(const float* __restrict__ p0, const float* __restrict__ p1,
                             const float* __restrict__ p2, const float* __restrict__ p3,
                             ushort* __restrict__ q0, ushort* __restrict__ q1,
                             ushort* __restrict__ q2, ushort* __restrict__ q3,
                             int n0, int n1, int n2, int n3){
  int i = blockIdx.x*256 + threadIdx.x;   // float4 index
  const float* src; ushort* dst; int loc;
  if (i < n0){ src=p0; dst=q0; loc=i; }
  else if (i < n0+n1){ src=p1; dst=q1; loc=i-n0; }
  else if (i < n0+n1+n2){ src=p2; dst=q2; loc=i-n0-n1; }
  else if (i < n0+n1+n2+n3){ src=p3; dst=q3; loc=i-n0-n1-n2; }
  else return;
  float4 v = reinterpret_cast<const float4*>(src)[loc];
  ushort4 o; o.x=f2h(v.x); o.y=f2h(v.y); o.z=f2h(v.z); o.w=f2h(v.w);
  reinterpret_cast<ushort4*>(dst)[loc] = o;
}

// ---------------- fold We with a_e, output-parallel, emit fp16 B [32][160] ----------------
__global__ void wfold_direct_kernel(const float* __restrict__ We0, const float* __restrict__ ae0,
                                    const float* __restrict__ We1, const float* __restrict__ ae1,
                                    const float* __restrict__ We2, const float* __restrict__ ae2,
                                    ushort* __restrict__ Bh){
  int t = blockIdx.x*256 + threadIdx.x;
  if (t >= 32*160) return;
  int j = t/160, d = t%160;
  float s = 0.f;
  if (j < 24 && d < 147){
    int l = j >> 3, h = j & 7;
    const float* We = (l==0) ? We0 : (l==1) ? We1 : We2;
    const float* ae = (l==0) ? ae0 : (l==1) ? ae1 : ae2;
    int C = (l==2) ? 32 : 64;
    for (int c=0;c<C;c++) s = fmaf(We[(size_t)(h*C+c)*147 + d], ae[h*C+c], s);
  }
  Bh[t] = f2h(s);
}

// ---------------- aEc[pos(e)][24] = ea_f32[e][147(pad160)] @ Bh[32][160]^T via MFMA ----------------
// 2 row-groups per wave (32 rows): 4 vectorized load chains in flight per k-step.
__device__ __forceinline__ f16x8 cvt8(f32x4u v0, f32x4u v1){
  f16x8 a;
  a[0]=(_Float16)v0[0]; a[1]=(_Float16)v0[1]; a[2]=(_Float16)v0[2]; a[3]=(_Float16)v0[3];
  a[4]=(_Float16)v1[0]; a[5]=(_Float16)v1[1]; a[6]=(_Float16)v1[2]; a[7]=(_Float16)v1[3];
  return a;
}

__global__ __launch_bounds__(256) void edge_alpha_mfma_kernel(const float* __restrict__ ea, const ushort* __restrict__ Bh,
                                                              const int* __restrict__ epos,
                                                              float* __restrict__ aEc, int E){
  int wave = threadIdx.x>>6, lane = threadIdx.x&63;
  int fr = lane&15, fq = lane>>4;
  int m0 = blockIdx.x*128 + wave*32;
  f32x4 accA0 = {0.f,0.f,0.f,0.f}, accA1 = {0.f,0.f,0.f,0.f};
  f32x4 accB0 = {0.f,0.f,0.f,0.f}, accB1 = {0.f,0.f,0.f,0.f};
  int rowA = m0 + fr;      if (rowA > E-1) rowA = E-1;
  int rowB = m0 + 16 + fr; if (rowB > E-1) rowB = E-1;
  const float*  arA = ea + (size_t)rowA*147;
  const float*  arB = ea + (size_t)rowB*147;
  const ushort* b0 = Bh + (size_t)fr*160      + fq*8;
  const ushort* b1 = Bh + (size_t)(16+fr)*160 + fq*8;
  #pragma unroll
  for (int k=0;k<128;k+=32){
    int c0 = k + fq*8;
    f32x4u vA0 = *(const f32x4u*)(arA + c0);
    f32x4u vA1 = *(const f32x4u*)(arA + c0 + 4);
    f32x4u vB0 = *(const f32x4u*)(arB + c0);
    f32x4u vB1 = *(const f32x4u*)(arB + c0 + 4);
    f16x8 aA = cvt8(vA0, vA1);
    f16x8 aB = cvt8(vB0, vB1);
    f16x8 p = *(const f16x8*)(b0 + k);
    f16x8 q = *(const f16x8*)(b1 + k);
    accA0 = __builtin_amdgcn_mfma_f32_16x16x32_f16(aA, p, accA0, 0, 0, 0);
    accA1 = __builtin_amdgcn_mfma_f32_16x16x32_f16(aA, q, accA1, 0, 0, 0);
    accB0 = __builtin_amdgcn_mfma_f32_16x16x32_f16(aB, p, accB0, 0, 0, 0);
    accB1 = __builtin_amdgcn_mfma_f32_16x16x32_f16(aB, q, accB1, 0, 0, 0);
  }
  {
    // k = 128 block: cols 128+fq*8 .. +7 ; row length 147
    f16x8 aA = {}, aB = {};
    if (fq < 2){
      int c0 = 128 + fq*8;
      aA = cvt8(*(const f32x4u*)(arA + c0), *(const f32x4u*)(arA + c0 + 4));
      aB = cvt8(*(const f32x4u*)(arB + c0), *(const f32x4u*)(arB + c0 + 4));
    } else if (fq == 2){
      aA[0]=(_Float16)arA[144]; aA[1]=(_Float16)arA[145]; aA[2]=(_Float16)arA[146];
      aB[0]=(_Float16)arB[144]; aB[1]=(_Float16)arB[145]; aB[2]=(_Float16)arB[146];
    }
    f16x8 p = *(const f16x8*)(b0 + 128);
    f16x8 q = *(const f16x8*)(b1 + 128);
    accA0 = __builtin_amdgcn_mfma_f32_16x16x32_f16(aA, p, accA0, 0, 0, 0);
    accA1 = __builtin_amdgcn_mfma_f32_16x16x32_f16(aA, q, accA1, 0, 0, 0);
    accB0 = __builtin_amdgcn_mfma_f32_16x16x32_f16(aB, p, accB0, 0, 0, 0);
    accB1 = __builtin_amdgcn_mfma_f32_16x16x32_f16(aB, q, accB1, 0, 0, 0);
  }
  #pragma unroll
  for (int j=0;j<4;j++){
    int rA = m0 + fq*4 + j;
    if (rA < E){
      int p = epos[rA];
      aEc[(size_t)p*24 + fr] = accA0[j];
      if (fr < 8) aEc[(size_t)p*24 + 16 + fr] = accA1[j];
    }
    int rB = m0 + 16 + fq*4 + j;
    if (rB < E){
      int p = epos[rB];
      aEc[(size_t)p*24 + fr] = accB0[j];
      if (fr < 8) aEc[(size_t)p*24 + 16 + fr] = accB1[j];
    }
  }
}

// ---------------- self-loop edge term (mean of incoming aEc rows, contiguous) ----------------
__global__ __launch_bounds__(192) void loop_alpha_all_kernel(const float* __restrict__ aEc, const int* __restrict__ row_ptr,
                                                             float* __restrict__ loopAE, int N){
  int n = blockIdx.x*8 + threadIdx.x/24;
  int j = threadIdx.x%24;
  if (n >= N) return;
  int row = row_ptr[n], end = row_ptr[n+1];
  float s = 0.f;
  for (int i=row;i<end;i++) s += aEc[(size_t)i*24 + j];
  loopAE[(size_t)n*24 + j] = s / fmaxf((float)(end-row), 1.0f);
}

// ---------------- fp16-MFMA GEMM, 8 waves (32x64 each), counted-vmcnt pipeline, fused alphaS/alphaD ----------------
template<int CPH>
__global__ __launch_bounds__(512) void gemm_mfma_kernel(const ushort* __restrict__ A, const ushort* __restrict__ B,
                                                        ushort* __restrict__ C,
                                                        const float* __restrict__ a_s, const float* __restrict__ a_d,
                                                        float* __restrict__ alphaS, float* __restrict__ alphaD,
                                                        int M, int Nn, int K, int NY){
  __shared__ ushort lds[128*64*4];   // As0|Bs0|As1|Bs1, 16KB each; Cs reuses (128*136 = 34.8KB)
  int nwg = gridDim.x;
  int bid = blockIdx.x;
  int q8 = nwg >> 3, r8 = nwg & 7;
  int xcd = bid & 7, loc = bid >> 3;
  int swz = (xcd < r8 ? xcd*(q8+1) : r8*(q8+1) + (xcd-r8)*q8) + loc;
  int m0 = (swz / NY) * 128, n0 = (swz % NY) * 128;

  int wave = threadIdx.x >> 6, lane = threadIdx.x & 63;
  int wr = wave >> 1, wc = wave & 1;   // wave tile: rows wr*32..+32, cols wc*64..+64
  f32x4 acc[2][4];
  #pragma unroll
  for (int m=0;m<2;m++)
    #pragma unroll
    for (int n=0;n<4;n++) acc[m][n] = (f32x4){0.f,0.f,0.f,0.f};

  int lrow = lane >> 3;
  int lcol = lane & 7;
  int srcChunk = lcol ^ lrow;     // inverse-swizzled global source (T2 via rule #21)
  int fr = lane & 15;
  int fq = lane >> 4;

  auto stage = [&](int buf, int k0){
    ushort* As = lds + buf*(128*64*2);
    ushort* Bs = As + 128*64;
    #pragma unroll
    for (int qq=0;qq<2;qq++){
      int r = qq*64 + wave*8 + lrow;
      int gr = m0 + r; if (gr > M-1) gr = M-1;
      __builtin_amdgcn_global_load_lds(AS1(A + (size_t)gr*K + k0 + srcChunk*8), AS3(&As[(qq*64 + wave*8)*64]), 16, 0, 0);
      __builtin_amdgcn_global_load_lds(AS1(B + (size_t)(n0 + r)*K + k0 + srcChunk*8), AS3(&Bs[(qq*64 + wave*8)*64]), 16, 0, 0);
    }
  };

  int nt = K >> 6;
  stage(0, 0);
  int buf = 0;
  for (int t=0; t<nt; ++t){
    if (t+1 < nt){
      stage(buf^1, (t+1)<<6);
      asm volatile("s_waitcnt vmcnt(4)" ::: "memory");
    } else {
      asm volatile("s_waitcnt vmcnt(0)" ::: "memory");
    }
    __builtin_amdgcn_s_barrier();
    __builtin_amdgcn_sched_barrier(0);
    const ushort* As = lds + buf*(128*64*2);
    const ushort* Bs = As + 128*64;
    #pragma unroll
    for (int kk=0; kk<64; kk+=32){
      f16x8 a[2], b[4];
      #pragma unroll
      for (int m=0;m<2;m++){
        int Ra = wr*32 + m*16 + fr;
        int ch = ((kk>>3) + fq) ^ (Ra & 7);
        a[m] = *(const f16x8*)&As[Ra*64 + ch*8];
      }
      #pragma unroll
      for (int n=0;n<4;n++){
        int Rb = wc*64 + n*16 + fr;
        int ch = ((kk>>3) + fq) ^ (Rb & 7);
        b[n] = *(const f16x8*)&Bs[Rb*64 + ch*8];
      }
      #pragma unroll
      for (int m=0;m<2;m++)
        #pragma unroll
        for (int n=0;n<4;n++)
          acc[m][n] = __builtin_amdgcn_mfma_f32_16x16x32_f16(a[m], b[n], acc[m][n], 0, 0, 0);
    }
    __builtin_amdgcn_s_barrier();
    buf ^= 1;
  }

  // stage C tile (fp16) into LDS (row padded to 136 to avoid bank conflicts), coalesced stores
  {
    ushort* Cs = lds;
    #pragma unroll
    for (int m=0;m<2;m++)
      #pragma unroll
      for (int j=0;j<4;j++){
        int rr = wr*32 + m*16 + fq*4 + j;
        #pragma unroll
        for (int n=0;n<4;n++)
          Cs[rr*136 + wc*64 + n*16 + fr] = f2h(acc[m][n][j]);
      }
    __builtin_amdgcn_s_barrier();
    int rbase = threadIdx.x >> 4;     // 0..31
    int cc = (threadIdx.x & 15)*8;
    #pragma unroll
    for (int p=0;p<4;p++){
      int rr = p*32 + rbase;
      int grow = m0 + rr;
      if (grow < M)
        *(f16x8*)(C + (size_t)grow*Nn + n0 + cc) = *(const f16x8*)&Cs[rr*136 + cc];
    }
  }

  // fused alphaS/alphaD epilogue (regs + shfl only; wave cols = full head(s))
  int colbase = n0 + wc*64;
  if (CPH == 64){
    int head = colbase >> 6;
    float asv[4], adv[4];
    #pragma unroll
    for (int n=0;n<4;n++){ int cih = n*16 + fr; asv[n] = a_s[head*64 + cih]; adv[n] = a_d[head*64 + cih]; }
    #pragma unroll
    for (int m=0;m<2;m++){
      float ps[4] = {0,0,0,0}, pd[4] = {0,0,0,0};
      #pragma unroll
      for (int n=0;n<4;n++)
        #pragma unroll
        for (int j=0;j<4;j++){ ps[j] = fmaf(acc[m][n][j], asv[n], ps[j]); pd[j] = fmaf(acc[m][n][j], adv[n], pd[j]); }
      #pragma unroll
      for (int off=1; off<16; off<<=1)
        #pragma unroll
        for (int j=0;j<4;j++){ ps[j] += __shfl_xor(ps[j], off); pd[j] += __shfl_xor(pd[j], off); }
      if (fr == 0){
        #pragma unroll
        for (int j=0;j<4;j++){
          int row = m0 + wr*32 + m*16 + fq*4 + j;
          if (row < M){ alphaS[(size_t)row*8 + head] = ps[j]; alphaD[(size_t)row*8 + head] = pd[j]; }
        }
      }
    }
  } else {
    int head0 = colbase >> 5;
    float asv[4], adv[4];
    #pragma unroll
    for (int n=0;n<4;n++){
      int h = head0 + (n>>1);
      int cih = (n&1)*16 + fr;
      asv[n] = a_s[h*32 + cih]; adv[n] = a_d[h*32 + cih];
    }
    #pragma unroll
    for (int m=0;m<2;m++){
      float psA[4]={0,0,0,0}, pdA[4]={0,0,0,0}, psB[4]={0,0,0,0}, pdB[4]={0,0,0,0};
      #pragma unroll
      for (int j=0;j<4;j++){
        #pragma unroll
        for (int n=0;n<2;n++){ psA[j] = fmaf(acc[m][n][j], asv[n], psA[j]); pdA[j] = fmaf(acc[m][n][j], adv[n], pdA[j]); }
        #pragma unroll
        for (int n=2;n<4;n++){ psB[j] = fmaf(acc[m][n][j], asv[n], psB[j]); pdB[j] = fmaf(acc[m][n][j], adv[n], pdB[j]); }
      }
      #pragma unroll
      for (int off=1; off<16; off<<=1)
        #pragma unroll
        for (int j=0;j<4;j++){
          psA[j] += __shfl_xor(psA[j], off); pdA[j] += __shfl_xor(pdA[j], off);
          psB[j] += __shfl_xor(psB[j], off); pdB[j] += __shfl_xor(pdB[j], off);
        }
      if (fr == 0){
        #pragma unroll
        for (int j=0;j<4;j++){
          int row = m0 + wr*32 + m*16 + fq*4 + j;
          if (row < M){
            alphaS[(size_t)row*8 + head0]     = psA[j]; alphaD[(size_t)row*8 + head0]     = pdA[j];
            alphaS[(size_t)row*8 + head0 + 1] = psB[j]; alphaD[(size_t)row*8 + head0 + 1] = pdB[j];
          }
        }
      }
    }
  }
}

// ---------------- aggregate: 2 nodes/wave, software-pipelined merged loop, fused exp ----------------
template<int V> struct vecT;
template<> struct vecT<8>{ typedef f16x8 T; };
template<> struct vecT<4>{ typedef f16x4 T; };

template<int V>
__device__ __forceinline__ void rowfma(typename vecT<V>::T v, float ex, float* acc){
  #pragma unroll
  for (int j=0;j<V;j++) acc[j] = fmaf(ex, (float)v[j], acc[j]);
}

template<int HC, int ELU>
__global__ __launch_bounds__(256) void aggregate_kernel(
    const ushort* __restrict__ xh, const float* __restrict__ alphaS, const float* __restrict__ alphaD,
    const float* __restrict__ aEc, const float* __restrict__ loopAE,
    const int* __restrict__ row_ptr, const int* __restrict__ csr_src,
    const float* __restrict__ bias, ushort* __restrict__ out, int N, int off){
  constexpr int V = HC/64;
  typedef typename vecT<V>::T vec;
  int w = blockIdx.x*4 + (threadIdx.x>>6);
  int nA = w*2, nB = w*2+1;
  if (nA >= N) return;
  bool hasB = (nB < N);
  int lane = threadIdx.x & 63;
  int h = lane >> 3;
  int cofs = V*lane;

  float adnA = alphaD[(size_t)nA*8 + h];
  float accA[V], accB[V];
  float denA, denB = 0.f;
  {
    float exs = __expf(leaky02(alphaS[(size_t)nA*8 + h] + adnA + loopAE[(size_t)nA*24 + off + h]));
    denA = exs;
    #pragma unroll
    for (int j=0;j<V;j++) accA[j] = 0.f;
    rowfma<V>(*(const vec*)(xh + (size_t)nA*HC + cofs), exs, accA);
  }
  #pragma unroll
  for (int j=0;j<V;j++) accB[j] = 0.f;
  float adnB = 0.f;
  int iA = row_ptr[nA], eAe = row_ptr[nA+1];
  int iB = eAe, eBe = eAe;
  if (hasB){
    adnB = alphaD[(size_t)nB*8 + h];
    float exs = __expf(leaky02(alphaS[(size_t)nB*8 + h] + adnB + loopAE[(size_t)nB*24 + off + h]));
    denB = exs;
    rowfma<V>(*(const vec*)(xh + (size_t)nB*HC + cofs), exs, accB);
    eBe = row_ptr[nB+1];
  }

  bool run = (iA+1 < eAe) && (iB+1 < eBe);
  int sA0=0,sA1=0,sB0=0,sB1=0;
  float gA0=0,gA1=0,gB0=0,gB1=0, tA0=0,tA1=0,tB0=0,tB1=0;
  vec vA0{}, vA1{}, vB0{}, vB1{};
  if (run){
    sA0=csr_src[iA]; sA1=csr_src[iA+1]; sB0=csr_src[iB]; sB1=csr_src[iB+1];
    gA0=alphaS[(size_t)sA0*8+h]; gA1=alphaS[(size_t)sA1*8+h];
    gB0=alphaS[(size_t)sB0*8+h]; gB1=alphaS[(size_t)sB1*8+h];
    tA0=aEc[(size_t)iA*24+off+h]; tA1=aEc[(size_t)(iA+1)*24+off+h];
    tB0=aEc[(size_t)iB*24+off+h]; tB1=aEc[(size_t)(iB+1)*24+off+h];
    vA0=*(const vec*)(xh+(size_t)sA0*HC+cofs); vA1=*(const vec*)(xh+(size_t)sA1*HC+cofs);
    vB0=*(const vec*)(xh+(size_t)sB0*HC+cofs); vB1=*(const vec*)(xh+(size_t)sB1*HC+cofs);
  }
  while (run){
    int jA = iA+2, jB = iB+2;
    bool nrun = (jA+1 < eAe) && (jB+1 < eBe);
    vec cA0=vA0, cA1=vA1, cB0=vB0, cB1=vB1;
    float eA0=__expf(leaky02(gA0+adnA+tA0));
    float eA1=__expf(leaky02(gA1+adnA+tA1));
    float eB0=__expf(leaky02(gB0+adnB+tB0));
    float eB1=__expf(leaky02(gB1+adnB+tB1));
    if (nrun){
      sA0=csr_src[jA]; sA1=csr_src[jA+1]; sB0=csr_src[jB]; sB1=csr_src[jB+1];
      gA0=alphaS[(size_t)sA0*8+h]; gA1=alphaS[(size_t)sA1*8+h];
      gB0=alphaS[(size_t)sB0*8+h]; gB1=alphaS[(size_t)sB1*8+h];
      tA0=aEc[(size_t)jA*24+off+h]; tA1=aEc[(size_t)(jA+1)*24+off+h];
      tB0=aEc[(size_t)jB*24+off+h]; tB1=aEc[(size_t)(jB+1)*24+off+h];
      vA0=*(const vec*)(xh+(size_t)sA0*HC+cofs); vA1=*(const vec*)(xh+(size_t)sA1*HC+cofs);
      vB0=*(const vec*)(xh+(size_t)sB0*HC+cofs); vB1=*(const vec*)(xh+(size_t)sB1*HC+cofs);
    }
    denA += eA0 + eA1; denB += eB0 + eB1;
    rowfma<V>(cA0, eA0, accA); rowfma<V>(cA1, eA1, accA);
    rowfma<V>(cB0, eB0, accB); rowfma<V>(cB1, eB1, accB);
    iA = jA; iB = jB;
    run = nrun;
  }
  for (; iA+1 < eAe; iA += 2){
    int s0 = csr_src[iA], s1 = csr_src[iA+1];
    float g0 = alphaS[(size_t)s0*8+h], g1 = alphaS[(size_t)s1*8+h];
    float t0 = aEc[(size_t)iA*24+off+h], t1 = aEc[(size_t)(iA+1)*24+off+h];
    vec v0 = *(const vec*)(xh+(size_t)s0*HC+cofs);
    vec v1 = *(const vec*)(xh+(size_t)s1*HC+cofs);
    float e0 = __expf(leaky02(g0+adnA+t0));
    float e1 = __expf(leaky02(g1+adnA+t1));
    denA += e0 + e1;
    rowfma<V>(v0, e0, accA); rowfma<V>(v1, e1, accA);
  }
  if (iA < eAe){
    int s = csr_src[iA];
    float g = alphaS[(size_t)s*8+h];
    float t = aEc[(size_t)iA*24+off+h];
    vec v = *(const vec*)(xh+(size_t)s*HC+cofs);
    float e = __expf(leaky02(g+adnA+t));
    denA += e;
    rowfma<V>(v, e, accA);
  }
  for (; iB+1 < eBe; iB += 2){
    int s0 = csr_src[iB], s1 = csr_src[iB+1];
    float g0 = alphaS[(size_t)s0*8+h], g1 = alphaS[(size_t)s1*8+h];
    float t0 = aEc[(size_t)iB*24+off+h], t1 = aEc[(size_t)(iB+1)*24+off+h];
    vec v0 = *(const vec*)(xh+(size_t)s0*HC+cofs);
    vec v1 = *(const vec*)(xh+(size_t)s1*HC+cofs);
    float e0 = __expf(leaky02(g0+adnB+t0));
    float e1 = __expf(leaky02(g1+adnB+t1));
    denB += e0 + e1;
    rowfma<V>(v0, e0, accB); rowfma<V>(v1, e1, accB);
  }
  if (iB < eBe){
    int s = csr_src[iB];
    float g = alphaS[(size_t)s*8+h];
    float t = aEc[(size_t)iB*24+off+h];
    vec v = *(const vec*)(xh+(size_t)s*HC+cofs);
    float e = __expf(leaky02(g+adnB+t));
    denB += e;
    rowfma<V>(v, e, accB);
  }

  float invA = 1.f/(denA + 1e-16f);
  {
    vec ov;
    #pragma unroll
    for (int j=0;j<V;j++){
      float o = accA[j]*invA + bias[cofs + j];
      if (ELU) o = (o > 0.f) ? o : (__expf(o) - 1.f);
      ov[j] = (_Float16)o;
    }
    *(vec*)(out + (size_t)nA*HC + cofs) = ov;
  }
  if (hasB){
    float invB = 1.f/(denB + 1e-16f);
    vec ov;
    #pragma unroll
    for (int j=0;j<V;j++){
      float o = accB[j]*invB + bias[cofs + j];
      if (ELU) o = (o > 0.f) ? o : (__expf(o) - 1.f);
      ov[j] = (_Float16)o;
    }
    *(vec*)(out + (size_t)nB*HC + cofs) = ov;
  }
}

// ---------------- node-parallel atomic mean pool (sums; final divides) ----------------
__global__ __launch_bounds__(256) void pool_sum_kernel(const ushort* __restrict__ h, const int* __restrict__ batch,
                                                       float* __restrict__ pooled, int N){
  __shared__ int bsh[128];
  int i0 = blockIdx.x*128;
  int i1 = min(i0+128, N);
  if (threadIdx.x < i1-i0) bsh[threadIdx.x] = batch[i0+threadIdx.x];
  __syncthreads();
  int c = threadIdx.x;
  int gprev = bsh[0];
  float s = 0.f;
  for (int i=i0;i<i1;i++){
    int g = bsh[i-i0];
    if (g != gprev){ atomicAdd(&pooled[gprev*256 + c], s); s = 0.f; gprev = g; }
    s += h2f(h[(size_t)i*256 + c]);
  }
  atomicAdd(&pooled[gprev*256 + c], s);
}

__device__ __forceinline__ int lower_bound_i(const int* a, int n, int key){
  int lo=0, hi=n;
  while (lo<hi){ int mid=(lo+hi)>>1; if (a[mid]<key) lo=mid+1; else hi=mid; }
  return lo;
}

__global__ void final_kernel(const float* __restrict__ pooled, const int* __restrict__ batch,
                             const float* __restrict__ Wc, const float* __restrict__ bc,
                             float* __restrict__ out, int N){
  int g = blockIdx.x; int j = threadIdx.x;
  if (j >= 32) return;
  int start = lower_bound_i(batch, N, g);
  int end   = lower_bound_i(batch, N, g+1);
  float invc = 1.f / fmaxf((float)(end-start), 1.f);
  const float* p = pooled + g*256;
  const float* w = Wc + (size_t)j*256;
  float s = 0.f;
  for (int c=0;c<256;c++) s = fmaf(p[c], w[c], s);
  out[g*32 + j] = s*invc + bc[j];
}

extern "C" void kernel_launch(void* const* d_in, const int* in_sizes, int n_in,
                              void* d_out, int out_size, void* d_ws, size_t ws_size,
                              hipStream_t stream){
  (void)n_in; (void)out_size; (void)ws_size;
  const float* x   = (const float*)d_in[0];
  const float* ea  = (const float*)d_in[1];
  const float* Wt[3]  = {(const float*)d_in[2],  (const float*)d_in[8],  (const float*)d_in[14]};
  const float* Wet[3] = {(const float*)d_in[3],  (const float*)d_in[9],  (const float*)d_in[15]};
  const float* ast[3] = {(const float*)d_in[4],  (const float*)d_in[10], (const float*)d_in[16]};
  const float* adt[3] = {(const float*)d_in[5],  (const float*)d_in[11], (const float*)d_in[17]};
  const float* aet[3] = {(const float*)d_in[6],  (const float*)d_in[12], (const float*)d_in[18]};
  const float* bt[3]  = {(const float*)d_in[7],  (const float*)d_in[13], (const float*)d_in[19]};
  const float* Wc  = (const float*)d_in[20];
  const float* bc  = (const float*)d_in[21];
  const int* ei    = (const int*)d_in[22];
  const int* batch = (const int*)d_in[23];
  int N = in_sizes[0] / 64;
  int E = in_sizes[1] / 147;
  const int* srcp = ei;
  const int* dstp = ei + E;

  char* w = (char*)d_ws;
  size_t off = 0;
  auto carve = [&](size_t bytes)->char*{ char* p = w + off; off += (bytes + 255) & ~(size_t)255; return p; };
  ushort* xh     = (ushort*)carve((size_t)N*512*2);
  ushort* hb     = (ushort*)carve((size_t)N*512*2);
  ushort* xb     = (ushort*)carve((size_t)N*64*2);
  ushort* Wb[3];
  Wb[0] = (ushort*)carve((size_t)512*64*2);
  Wb[1] = (ushort*)carve((size_t)512*512*2);
  Wb[2] = (ushort*)carve((size_t)256*512*2);
  ushort* wfBh   = (ushort*)carve((size_t)32*160*2);
  float*  aEc    = (float*) carve((size_t)E*24*4);
  float*  loopAE = (float*) carve((size_t)N*24*4);
  float*  alphaS = (float*) carve((size_t)N*8*4);
  float*  alphaD = (float*) carve((size_t)N*8*4);
  int*    row_ptr= (int*)   carve((size_t)(N+1)*4);
  int*    epos   = (int*)   carve((size_t)E*4);
  int*    csr_src= (int*)   carve((size_t)E*4);
  int*    bsum   = (int*)   carve((size_t)256*4);
  // zero-region: pooled | cnt | cursor (single memset)
  char*   zbase  = carve(0);
  float*  pooled = (float*) carve((size_t)128*256*4);
  int*    cnt    = (int*)   carve((size_t)N*4);
  int*    cursor = (int*)   carve((size_t)N*4);
  char*   zend   = carve(0);

  hipMemsetAsync(zbase, 0, (size_t)(zend - zbase), stream);

  int nscan = (N+255)/256;
  count_kernel  <<<(E+255)/256, 256, 0, stream>>>(dstp, cnt, E);
  scanA_kernel  <<<nscan, 256, 0, stream>>>(cnt, bsum, N);
  scanB_kernel  <<<1, 256, 0, stream>>>(bsum, nscan);
  scanC_kernel  <<<nscan, 256, 0, stream>>>(cnt, bsum, row_ptr, N);
  scatter_kernel<<<(E+255)/256, 256, 0, stream>>>(srcp, dstp, row_ptr, cursor, epos, csr_src, E);

  wfold_direct_kernel<<<(32*160+255)/256, 256, 0, stream>>>(Wet[0], aet[0], Wet[1], aet[1], Wet[2], aet[2], wfBh);

  conv4_kernel<<<(N*16 + 8192 + 65536 + 32768 + 255)/256, 256, 0, stream>>>(
      x, Wt[0], Wt[1], Wt[2], xb, Wb[0], Wb[1], Wb[2], N*16, 8192, 65536, 32768);

  edge_alpha_mfma_kernel<<<(E+127)/128, 256, 0, stream>>>(ea, wfBh, epos, aEc, E);
  loop_alpha_all_kernel <<<(N+7)/8, 192, 0, stream>>>(aEc, row_ptr, loopAE, N);

  const int HCs[3]  = {512, 512, 256};
  const int CINs[3] = {64, 512, 512};
  int nrow = (N+127)/128;
  for (int l=0; l<3; l++){
    int HC = HCs[l], CIN = CINs[l];
    const ushort* Ain = (l==0) ? xb : hb;
    int NY = HC/128;
    int nwg = nrow * NY;
    if (HC==512) gemm_mfma_kernel<64><<<nwg, 512, 0, stream>>>(Ain, Wb[l], xh, ast[l], adt[l], alphaS, alphaD, N, HC, CIN, NY);
    else         gemm_mfma_kernel<32><<<nwg, 512, 0, stream>>>(Ain, Wb[l], xh, ast[l], adt[l], alphaS, alphaD, N, HC, CIN, NY);
    int ablocks = (N + 7) / 8;   // 4 waves/block, 2 nodes/wave
    if (l==0)
      aggregate_kernel<512,1><<<ablocks, 256, 0, stream>>>(xh, alphaS, alphaD, aEc, loopAE, row_ptr, csr_src, bt[l], hb, N, 0);
    else if (l==1)
      aggregate_kernel<512,1><<<ablocks, 256, 0, stream>>>(xh, alphaS, alphaD, aEc, loopAE, row_ptr, csr_src, bt[l], hb, N, 8);
    else
      aggregate_kernel<256,0><<<ablocks, 256, 0, stream>>>(xh, alphaS, alphaD, aEc, loopAE, row_ptr, csr_src, bt[l], hb, N, 16);
  }
  pool_sum_kernel<<<(N+127)/128, 256, 0, stream>>>(hb, batch, pooled, N);
  final_kernel<<<128, 64, 0, stream>>>(pooled, batch, Wc, bc, (float*)d_out, N);
}

// Round 17
// 410.000 us; speedup vs baseline: 1.0236x; 1.0236x over previous
//
#include <hip/hip_runtime.h>
#include <hip/hip_bf16.h>
#include <math.h>

typedef __attribute__((ext_vector_type(8))) _Float16 f16x8;
typedef __attribute__((ext_vector_type(4))) _Float16 f16x4;
typedef __attribute__((ext_vector_type(4))) float f32x4;
typedef __attribute__((ext_vector_type(4), aligned(4))) float f32x4u;   // 4B-aligned vector load

#define AS1(p) ((const __attribute__((address_space(1))) void*)(p))
#define AS3(p) ((__attribute__((address_space(3))) void*)(p))

__device__ __forceinline__ float leaky02(float x){ return x > 0.f ? x : 0.2f*x; }
__device__ __forceinline__ ushort f2h(float f){ _Float16 h = (_Float16)f; return *(ushort*)&h; }
__device__ __forceinline__ float h2f(ushort u){ _Float16 h = *(_Float16*)&u; return (float)h; }

// ---------------- CSR build over dst ----------------
__global__ void count_kernel(const int* __restrict__ dst, int* __restrict__ cnt, int E){
  int e = blockIdx.x*blockDim.x + threadIdx.x;
  if (e < E) atomicAdd(&cnt[dst[e]], 1);
}

__global__ void scanA_kernel(const int* __restrict__ cnt, int* __restrict__ bsum, int N){
  __shared__ int sd[256];
  int i = blockIdx.x*256 + threadIdx.x;
  sd[threadIdx.x] = (i<N) ? cnt[i] : 0;
  __syncthreads();
  for (int off=128; off>0; off>>=1){
    if (threadIdx.x < off) sd[threadIdx.x] += sd[threadIdx.x+off];
    __syncthreads();
  }
  if (threadIdx.x==0) bsum[blockIdx.x] = sd[0];
}
__global__ void scanB_kernel(int* __restrict__ bsum, int B){
  __shared__ int sd[256];
  int t = threadIdx.x;
  int v = (t<B) ? bsum[t] : 0;
  sd[t] = v;
  __syncthreads();
  for (int off=1; off<256; off<<=1){
    int u = (t>=off) ? sd[t-off] : 0;
    __syncthreads();
    sd[t] += u;
    __syncthreads();
  }
  if (t<B) bsum[t] = sd[t] - v;   // exclusive
}
__global__ void scanC_kernel(const int* __restrict__ cnt, const int* __restrict__ bsum,
                             int* __restrict__ row_ptr, int N){
  __shared__ int sd[256];
  int i = blockIdx.x*256 + threadIdx.x;
  int v = (i<N) ? cnt[i] : 0;
  sd[threadIdx.x] = v;
  __syncthreads();
  for (int off=1; off<256; off<<=1){
    int u = (threadIdx.x>=off) ? sd[threadIdx.x-off] : 0;
    __syncthreads();
    sd[threadIdx.x] += u;
    __syncthreads();
  }
  if (i < N) row_ptr[i+1] = sd[threadIdx.x] + bsum[blockIdx.x];
  if (i == 0) row_ptr[0] = 0;
}

__global__ void scatter_kernel(const int* __restrict__ src, const int* __restrict__ dst,
                               const int* __restrict__ row_ptr, int* __restrict__ cursor,
                               int* __restrict__ epos, int* __restrict__ csr_src, int E){
  int e = blockIdx.x*blockDim.x + threadIdx.x;
  if (e < E){
    int d = dst[e];
    int pos = row_ptr[d] + atomicAdd(&cursor[d], 1);
    epos[e] = pos;
    csr_src[pos] = src[e];
  }
}

// ---------------- fp32 -> fp16 conversion, 4 segments in one launch ----------------
__global__ void conv4_kernel(const float* __restrict__ p0, const float* __restrict__ p1,
                             const float* __restrict__ p2, const float* __restrict__ p3,
                             ushort* __restrict__ q0, ushort* __restrict__ q1,
                             ushort* __restrict__ q2, ushort* __restrict__ q3,
                             int n0, int n1, int n2, int n3){
  int i = blockIdx.x*256 + threadIdx.x;   // float4 index
  const float* src; ushort* dst; int loc;
  if (i < n0){ src=p0; dst=q0; loc=i; }
  else if (i < n0+n1){ src=p1; dst=q1; loc=i-n0; }
  else if (i < n0+n1+n2){ src=p2; dst=q2; loc=i-n0-n1; }
  else if (i < n0+n1+n2+n3){ src=p3; dst=q3; loc=i-n0-n1-n2; }
  else return;
  float4 v = reinterpret_cast<const float4*>(src)[loc];
  ushort4 o; o.x=f2h(v.x); o.y=f2h(v.y); o.z=f2h(v.z); o.w=f2h(v.w);
  reinterpret_cast<ushort4*>(dst)[loc] = o;
}

// ---------------- fold We with a_e, output-parallel, emit fp16 B [32][160] ----------------
__global__ void wfold_direct_kernel(const float* __restrict__ We0, const float* __restrict__ ae0,
                                    const float* __restrict__ We1, const float* __restrict__ ae1,
                                    const float* __restrict__ We2, const float* __restrict__ ae2,
                                    ushort* __restrict__ Bh){
  int t = blockIdx.x*256 + threadIdx.x;
  if (t >= 32*160) return;
  int j = t/160, d = t%160;
  float s = 0.f;
  if (j < 24 && d < 147){
    int l = j >> 3, h = j & 7;
    const float* We = (l==0) ? We0 : (l==1) ? We1 : We2;
    const float* ae = (l==0) ? ae0 : (l==1) ? ae1 : ae2;
    int C = (l==2) ? 32 : 64;
    for (int c=0;c<C;c++) s = fmaf(We[(size_t)(h*C+c)*147 + d], ae[h*C+c], s);
  }
  Bh[t] = f2h(s);
}

// ---------------- aEc[pos(e)][24] = ea_f32[e][147(pad160)] @ Bh[32][160]^T via MFMA ----------------
// ALL row loads batched into registers first (single memory round-trip), then cvt+MFMA.
__device__ __forceinline__ f16x8 cvt8(f32x4u v0, f32x4u v1){
  f16x8 a;
  a[0]=(_Float16)v0[0]; a[1]=(_Float16)v0[1]; a[2]=(_Float16)v0[2]; a[3]=(_Float16)v0[3];
  a[4]=(_Float16)v1[0]; a[5]=(_Float16)v1[1]; a[6]=(_Float16)v1[2]; a[7]=(_Float16)v1[3];
  return a;
}

__global__ __launch_bounds__(256, 1) void edge_alpha_mfma_kernel(const float* __restrict__ ea, const ushort* __restrict__ Bh,
                                                                 const int* __restrict__ epos,
                                                                 float* __restrict__ aEc, int E){
  int wave = threadIdx.x>>6, lane = threadIdx.x&63;
  int fr = lane&15, fq = lane>>4;
  int m0 = blockIdx.x*64 + wave*16;
  int row = m0 + fr; if (row > E-1) row = E-1;
  const float* ar = ea + (size_t)row*147;

  // batch all 10 vector loads (cols k+fq*8, k=0,32,64,96,128-tail) before any compute
  f32x4u L[10];
  #pragma unroll
  for (int i=0;i<4;i++){
    int c0 = i*32 + fq*8;
    L[2*i]   = *(const f32x4u*)(ar + c0);
    L[2*i+1] = *(const f32x4u*)(ar + c0 + 4);
  }
  if (fq < 2){
    int c0 = 128 + fq*8;
    L[8] = *(const f32x4u*)(ar + c0);
    L[9] = *(const f32x4u*)(ar + c0 + 4);
  } else if (fq == 2){
    L[8] = (f32x4u){ar[144], ar[145], ar[146], 0.f};
    L[9] = (f32x4u){0.f, 0.f, 0.f, 0.f};
  } else {
    L[8] = (f32x4u){0.f, 0.f, 0.f, 0.f};
    L[9] = (f32x4u){0.f, 0.f, 0.f, 0.f};
  }

  f32x4 acc0 = {0.f,0.f,0.f,0.f}, acc1 = {0.f,0.f,0.f,0.f};
  const ushort* b0 = Bh + (size_t)fr*160      + fq*8;
  const ushort* b1 = Bh + (size_t)(16+fr)*160 + fq*8;
  #pragma unroll
  for (int i=0;i<5;i++){
    f16x8 a = cvt8(L[2*i], L[2*i+1]);
    f16x8 p = *(const f16x8*)(b0 + i*32);
    f16x8 q = *(const f16x8*)(b1 + i*32);
    acc0 = __builtin_amdgcn_mfma_f32_16x16x32_f16(a, p, acc0, 0, 0, 0);
    acc1 = __builtin_amdgcn_mfma_f32_16x16x32_f16(a, q, acc1, 0, 0, 0);
  }
  #pragma unroll
  for (int j=0;j<4;j++){
    int r = m0 + fq*4 + j;
    if (r < E){
      int p = epos[r];
      aEc[(size_t)p*24 + fr] = acc0[j];
      if (fr < 8) aEc[(size_t)p*24 + 16 + fr] = acc1[j];
    }
  }
}

// ---------------- self-loop edge term (mean of incoming aEc rows, contiguous) ----------------
__global__ __launch_bounds__(192) void loop_alpha_all_kernel(const float* __restrict__ aEc, const int* __restrict__ row_ptr,
                                                             float* __restrict__ loopAE, int N){
  int n = blockIdx.x*8 + threadIdx.x/24;
  int j = threadIdx.x%24;
  if (n >= N) return;
  int row = row_ptr[n], end = row_ptr[n+1];
  float s = 0.f;
  for (int i=row;i<end;i++) s += aEc[(size_t)i*24 + j];
  loopAE[(size_t)n*24 + j] = s / fmaxf((float)(end-row), 1.0f);
}

// ---------------- fp16-MFMA GEMM, 8 waves (32x64 each), counted-vmcnt pipeline, fused alphaS/alphaD ----------------
template<int CPH>
__global__ __launch_bounds__(512) void gemm_mfma_kernel(const ushort* __restrict__ A, const ushort* __restrict__ B,
                                                        ushort* __restrict__ C,
                                                        const float* __restrict__ a_s, const float* __restrict__ a_d,
                                                        float* __restrict__ alphaS, float* __restrict__ alphaD,
                                                        int M, int Nn, int K, int NY){
  __shared__ ushort lds[128*64*4];   // As0|Bs0|As1|Bs1, 16KB each; Cs reuses (128*136 = 34.8KB)
  int nwg = gridDim.x;
  int bid = blockIdx.x;
  int q8 = nwg >> 3, r8 = nwg & 7;
  int xcd = bid & 7, loc = bid >> 3;
  int swz = (xcd < r8 ? xcd*(q8+1) : r8*(q8+1) + (xcd-r8)*q8) + loc;
  int m0 = (swz / NY) * 128, n0 = (swz % NY) * 128;

  int wave = threadIdx.x >> 6, lane = threadIdx.x & 63;
  int wr = wave >> 1, wc = wave & 1;   // wave tile: rows wr*32..+32, cols wc*64..+64
  f32x4 acc[2][4];
  #pragma unroll
  for (int m=0;m<2;m++)
    #pragma unroll
    for (int n=0;n<4;n++) acc[m][n] = (f32x4){0.f,0.f,0.f,0.f};

  int lrow = lane >> 3;
  int lcol = lane & 7;
  int srcChunk = lcol ^ lrow;     // inverse-swizzled global source (T2 via rule #21)
  int fr = lane & 15;
  int fq = lane >> 4;

  auto stage = [&](int buf, int k0){
    ushort* As = lds + buf*(128*64*2);
    ushort* Bs = As + 128*64;
    #pragma unroll
    for (int qq=0;qq<2;qq++){
      int r = qq*64 + wave*8 + lrow;
      int gr = m0 + r; if (gr > M-1) gr = M-1;
      __builtin_amdgcn_global_load_lds(AS1(A + (size_t)gr*K + k0 + srcChunk*8), AS3(&As[(qq*64 + wave*8)*64]), 16, 0, 0);
      __builtin_amdgcn_global_load_lds(AS1(B + (size_t)(n0 + r)*K + k0 + srcChunk*8), AS3(&Bs[(qq*64 + wave*8)*64]), 16, 0, 0);
    }
  };

  int nt = K >> 6;
  stage(0, 0);
  int buf = 0;
  for (int t=0; t<nt; ++t){
    if (t+1 < nt){
      stage(buf^1, (t+1)<<6);
      asm volatile("s_waitcnt vmcnt(4)" ::: "memory");
    } else {
      asm volatile("s_waitcnt vmcnt(0)" ::: "memory");
    }
    __builtin_amdgcn_s_barrier();
    __builtin_amdgcn_sched_barrier(0);
    const ushort* As = lds + buf*(128*64*2);
    const ushort* Bs = As + 128*64;
    #pragma unroll
    for (int kk=0; kk<64; kk+=32){
      f16x8 a[2], b[4];
      #pragma unroll
      for (int m=0;m<2;m++){
        int Ra = wr*32 + m*16 + fr;
        int ch = ((kk>>3) + fq) ^ (Ra & 7);
        a[m] = *(const f16x8*)&As[Ra*64 + ch*8];
      }
      #pragma unroll
      for (int n=0;n<4;n++){
        int Rb = wc*64 + n*16 + fr;
        int ch = ((kk>>3) + fq) ^ (Rb & 7);
        b[n] = *(const f16x8*)&Bs[Rb*64 + ch*8];
      }
      #pragma unroll
      for (int m=0;m<2;m++)
        #pragma unroll
        for (int n=0;n<4;n++)
          acc[m][n] = __builtin_amdgcn_mfma_f32_16x16x32_f16(a[m], b[n], acc[m][n], 0, 0, 0);
    }
    __builtin_amdgcn_s_barrier();
    buf ^= 1;
  }

  // stage C tile (fp16) into LDS (row padded to 136 to avoid bank conflicts), coalesced stores
  {
    ushort* Cs = lds;
    #pragma unroll
    for (int m=0;m<2;m++)
      #pragma unroll
      for (int j=0;j<4;j++){
        int rr = wr*32 + m*16 + fq*4 + j;
        #pragma unroll
        for (int n=0;n<4;n++)
          Cs[rr*136 + wc*64 + n*16 + fr] = f2h(acc[m][n][j]);
      }
    __builtin_amdgcn_s_barrier();
    int rbase = threadIdx.x >> 4;     // 0..31
    int cc = (threadIdx.x & 15)*8;
    #pragma unroll
    for (int p=0;p<4;p++){
      int rr = p*32 + rbase;
      int grow = m0 + rr;
      if (grow < M)
        *(f16x8*)(C + (size_t)grow*Nn + n0 + cc) = *(const f16x8*)&Cs[rr*136 + cc];
    }
  }

  // fused alphaS/alphaD epilogue (regs + shfl only; wave cols = full head(s))
  int colbase = n0 + wc*64;
  if (CPH == 64){
    int head = colbase >> 6;
    float asv[4], adv[4];
    #pragma unroll
    for (int n=0;n<4;n++){ int cih = n*16 + fr; asv[n] = a_s[head*64 + cih]; adv[n] = a_d[head*64 + cih]; }
    #pragma unroll
    for (int m=0;m<2;m++){
      float ps[4] = {0,0,0,0}, pd[4] = {0,0,0,0};
      #pragma unroll
      for (int n=0;n<4;n++)
        #pragma unroll
        for (int j=0;j<4;j++){ ps[j] = fmaf(acc[m][n][j], asv[n], ps[j]); pd[j] = fmaf(acc[m][n][j], adv[n], pd[j]); }
      #pragma unroll
      for (int off=1; off<16; off<<=1)
        #pragma unroll
        for (int j=0;j<4;j++){ ps[j] += __shfl_xor(ps[j], off); pd[j] += __shfl_xor(pd[j], off); }
      if (fr == 0){
        #pragma unroll
        for (int j=0;j<4;j++){
          int row = m0 + wr*32 + m*16 + fq*4 + j;
          if (row < M){ alphaS[(size_t)row*8 + head] = ps[j]; alphaD[(size_t)row*8 + head] = pd[j]; }
        }
      }
    }
  } else {
    int head0 = colbase >> 5;
    float asv[4], adv[4];
    #pragma unroll
    for (int n=0;n<4;n++){
      int h = head0 + (n>>1);
      int cih = (n&1)*16 + fr;
      asv[n] = a_s[h*32 + cih]; adv[n] = a_d[h*32 + cih];
    }
    #pragma unroll
    for (int m=0;m<2;m++){
      float psA[4]={0,0,0,0}, pdA[4]={0,0,0,0}, psB[4]={0,0,0,0}, pdB[4]={0,0,0,0};
      #pragma unroll
      for (int j=0;j<4;j++){
        #pragma unroll
        for (int n=0;n<2;n++){ psA[j] = fmaf(acc[m][n][j], asv[n], psA[j]); pdA[j] = fmaf(acc[m][n][j], adv[n], pdA[j]); }
        #pragma unroll
        for (int n=2;n<4;n++){ psB[j] = fmaf(acc[m][n][j], asv[n], psB[j]); pdB[j] = fmaf(acc[m][n][j], adv[n], pdB[j]); }
      }
      #pragma unroll
      for (int off=1; off<16; off<<=1)
        #pragma unroll
        for (int j=0;j<4;j++){
          psA[j] += __shfl_xor(psA[j], off); pdA[j] += __shfl_xor(pdA[j], off);
          psB[j] += __shfl_xor(psB[j], off); pdB[j] += __shfl_xor(pdB[j], off);
        }
      if (fr == 0){
        #pragma unroll
        for (int j=0;j<4;j++){
          int row = m0 + wr*32 + m*16 + fq*4 + j;
          if (row < M){
            alphaS[(size_t)row*8 + head0]     = psA[j]; alphaD[(size_t)row*8 + head0]     = pdA[j];
            alphaS[(size_t)row*8 + head0 + 1] = psB[j]; alphaD[(size_t)row*8 + head0 + 1] = pdB[j];
          }
        }
      }
    }
  }
}

// ---------------- aggregate: 2 nodes/wave, software-pipelined merged loop, fused exp ----------------
template<int V> struct vecT;
template<> struct vecT<8>{ typedef f16x8 T; };
template<> struct vecT<4>{ typedef f16x4 T; };

template<int V>
__device__ __forceinline__ void rowfma(typename vecT<V>::T v, float ex, float* acc){
  #pragma unroll
  for (int j=0;j<V;j++) acc[j] = fmaf(ex, (float)v[j], acc[j]);
}

template<int HC, int ELU>
__global__ __launch_bounds__(256) void aggregate_kernel(
    const ushort* __restrict__ xh, const float* __restrict__ alphaS, const float* __restrict__ alphaD,
    const float* __restrict__ aEc, const float* __restrict__ loopAE,
    const int* __restrict__ row_ptr, const int* __restrict__ csr_src,
    const float* __restrict__ bias, ushort* __restrict__ out, int N, int off){
  constexpr int V = HC/64;
  typedef typename vecT<V>::T vec;
  int w = blockIdx.x*4 + (threadIdx.x>>6);
  int nA = w*2, nB = w*2+1;
  if (nA >= N) return;
  bool hasB = (nB < N);
  int lane = threadIdx.x & 63;
  int h = lane >> 3;
  int cofs = V*lane;

  float adnA = alphaD[(size_t)nA*8 + h];
  float accA[V], accB[V];
  float denA, denB = 0.f;
  {
    float exs = __expf(leaky02(alphaS[(size_t)nA*8 + h] + adnA + loopAE[(size_t)nA*24 + off + h]));
    denA = exs;
    #pragma unroll
    for (int j=0;j<V;j++) accA[j] = 0.f;
    rowfma<V>(*(const vec*)(xh + (size_t)nA*HC + cofs), exs, accA);
  }
  #pragma unroll
  for (int j=0;j<V;j++) accB[j] = 0.f;
  float adnB = 0.f;
  int iA = row_ptr[nA], eAe = row_ptr[nA+1];
  int iB = eAe, eBe = eAe;
  if (hasB){
    adnB = alphaD[(size_t)nB*8 + h];
    float exs = __expf(leaky02(alphaS[(size_t)nB*8 + h] + adnB + loopAE[(size_t)nB*24 + off + h]));
    denB = exs;
    rowfma<V>(*(const vec*)(xh + (size_t)nB*HC + cofs), exs, accB);
    eBe = row_ptr[nB+1];
  }

  bool run = (iA+1 < eAe) && (iB+1 < eBe);
  int sA0=0,sA1=0,sB0=0,sB1=0;
  float gA0=0,gA1=0,gB0=0,gB1=0, tA0=0,tA1=0,tB0=0,tB1=0;
  vec vA0{}, vA1{}, vB0{}, vB1{};
  if (run){
    sA0=csr_src[iA]; sA1=csr_src[iA+1]; sB0=csr_src[iB]; sB1=csr_src[iB+1];
    gA0=alphaS[(size_t)sA0*8+h]; gA1=alphaS[(size_t)sA1*8+h];
    gB0=alphaS[(size_t)sB0*8+h]; gB1=alphaS[(size_t)sB1*8+h];
    tA0=aEc[(size_t)iA*24+off+h]; tA1=aEc[(size_t)(iA+1)*24+off+h];
    tB0=aEc[(size_t)iB*24+off+h]; tB1=aEc[(size_t)(iB+1)*24+off+h];
    vA0=*(const vec*)(xh+(size_t)sA0*HC+cofs); vA1=*(const vec*)(xh+(size_t)sA1*HC+cofs);
    vB0=*(const vec*)(xh+(size_t)sB0*HC+cofs); vB1=*(const vec*)(xh+(size_t)sB1*HC+cofs);
  }
  while (run){
    int jA = iA+2, jB = iB+2;
    bool nrun = (jA+1 < eAe) && (jB+1 < eBe);
    vec cA0=vA0, cA1=vA1, cB0=vB0, cB1=vB1;
    float eA0=__expf(leaky02(gA0+adnA+tA0));
    float eA1=__expf(leaky02(gA1+adnA+tA1));
    float eB0=__expf(leaky02(gB0+adnB+tB0));
    float eB1=__expf(leaky02(gB1+adnB+tB1));
    if (nrun){
      sA0=csr_src[jA]; sA1=csr_src[jA+1]; sB0=csr_src[jB]; sB1=csr_src[jB+1];
      gA0=alphaS[(size_t)sA0*8+h]; gA1=alphaS[(size_t)sA1*8+h];
      gB0=alphaS[(size_t)sB0*8+h]; gB1=alphaS[(size_t)sB1*8+h];
      tA0=aEc[(size_t)jA*24+off+h]; tA1=aEc[(size_t)(jA+1)*24+off+h];
      tB0=aEc[(size_t)jB*24+off+h]; tB1=aEc[(size_t)(jB+1)*24+off+h];
      vA0=*(const vec*)(xh+(size_t)sA0*HC+cofs); vA1=*(const vec*)(xh+(size_t)sA1*HC+cofs);
      vB0=*(const vec*)(xh+(size_t)sB0*HC+cofs); vB1=*(const vec*)(xh+(size_t)sB1*HC+cofs);
    }
    denA += eA0 + eA1; denB += eB0 + eB1;
    rowfma<V>(cA0, eA0, accA); rowfma<V>(cA1, eA1, accA);
    rowfma<V>(cB0, eB0, accB); rowfma<V>(cB1, eB1, accB);
    iA = jA; iB = jB;
    run = nrun;
  }
  for (; iA+1 < eAe; iA += 2){
    int s0 = csr_src[iA], s1 = csr_src[iA+1];
    float g0 = alphaS[(size_t)s0*8+h], g1 = alphaS[(size_t)s1*8+h];
    float t0 = aEc[(size_t)iA*24+off+h], t1 = aEc[(size_t)(iA+1)*24+off+h];
    vec v0 = *(const vec*)(xh+(size_t)s0*HC+cofs);
    vec v1 = *(const vec*)(xh+(size_t)s1*HC+cofs);
    float e0 = __expf(leaky02(g0+adnA+t0));
    float e1 = __expf(leaky02(g1+adnA+t1));
    denA += e0 + e1;
    rowfma<V>(v0, e0, accA); rowfma<V>(v1, e1, accA);
  }
  if (iA < eAe){
    int s = csr_src[iA];
    float g = alphaS[(size_t)s*8+h];
    float t = aEc[(size_t)iA*24+off+h];
    vec v = *(const vec*)(xh+(size_t)s*HC+cofs);
    float e = __expf(leaky02(g+adnA+t));
    denA += e;
    rowfma<V>(v, e, accA);
  }
  for (; iB+1 < eBe; iB += 2){
    int s0 = csr_src[iB], s1 = csr_src[iB+1];
    float g0 = alphaS[(size_t)s0*8+h], g1 = alphaS[(size_t)s1*8+h];
    float t0 = aEc[(size_t)iB*24+off+h], t1 = aEc[(size_t)(iB+1)*24+off+h];
    vec v0 = *(const vec*)(xh+(size_t)s0*HC+cofs);
    vec v1 = *(const vec*)(xh+(size_t)s1*HC+cofs);
    float e0 = __expf(leaky02(g0+adnB+t0));
    float e1 = __expf(leaky02(g1+adnB+t1));
    denB += e0 + e1;
    rowfma<V>(v0, e0, accB); rowfma<V>(v1, e1, accB);
  }
  if (iB < eBe){
    int s = csr_src[iB];
    float g = alphaS[(size_t)s*8+h];
    float t = aEc[(size_t)iB*24+off+h];
    vec v = *(const vec*)(xh+(size_t)s*HC+cofs);
    float e = __expf(leaky02(g+adnB+t));
    denB += e;
    rowfma<V>(v, e, accB);
  }

  float invA = 1.f/(denA + 1e-16f);
  {
    vec ov;
    #pragma unroll
    for (int j=0;j<V;j++){
      float o = accA[j]*invA + bias[cofs + j];
      if (ELU) o = (o > 0.f) ? o : (__expf(o) - 1.f);
      ov[j] = (_Float16)o;
    }
    *(vec*)(out + (size_t)nA*HC + cofs) = ov;
  }
  if (hasB){
    float invB = 1.f/(denB + 1e-16f);
    vec ov;
    #pragma unroll
    for (int j=0;j<V;j++){
      float o = accB[j]*invB + bias[cofs + j];
      if (ELU) o = (o > 0.f) ? o : (__expf(o) - 1.f);
      ov[j] = (_Float16)o;
    }
    *(vec*)(out + (size_t)nB*HC + cofs) = ov;
  }
}

// ---------------- node-parallel atomic mean pool (sums; final divides) ----------------
__global__ __launch_bounds__(256) void pool_sum_kernel(const ushort* __restrict__ h, const int* __restrict__ batch,
                                                       float* __restrict__ pooled, int N){
  __shared__ int bsh[128];
  int i0 = blockIdx.x*128;
  int i1 = min(i0+128, N);
  if (threadIdx.x < i1-i0) bsh[threadIdx.x] = batch[i0+threadIdx.x];
  __syncthreads();
  int c = threadIdx.x;
  int gprev = bsh[0];
  float s = 0.f;
  for (int i=i0;i<i1;i++){
    int g = bsh[i-i0];
    if (g != gprev){ atomicAdd(&pooled[gprev*256 + c], s); s = 0.f; gprev = g; }
    s += h2f(h[(size_t)i*256 + c]);
  }
  atomicAdd(&pooled[gprev*256 + c], s);
}

__device__ __forceinline__ int lower_bound_i(const int* a, int n, int key){
  int lo=0, hi=n;
  while (lo<hi){ int mid=(lo+hi)>>1; if (a[mid]<key) lo=mid+1; else hi=mid; }
  return lo;
}

__global__ void final_kernel(const float* __restrict__ pooled, const int* __restrict__ batch,
                             const float* __restrict__ Wc, const float* __restrict__ bc,
                             float* __restrict__ out, int N){
  int g = blockIdx.x; int j = threadIdx.x;
  if (j >= 32) return;
  int start = lower_bound_i(batch, N, g);
  int end   = lower_bound_i(batch, N, g+1);
  float invc = 1.f / fmaxf((float)(end-start), 1.f);
  const float* p = pooled + g*256;
  const float* w = Wc + (size_t)j*256;
  float s = 0.f;
  for (int c=0;c<256;c++) s = fmaf(p[c], w[c], s);
  out[g*32 + j] = s*invc + bc[j];
}

extern "C" void kernel_launch(void* const* d_in, const int* in_sizes, int n_in,
                              void* d_out, int out_size, void* d_ws, size_t ws_size,
                              hipStream_t stream){
  (void)n_in; (void)out_size; (void)ws_size;
  const float* x   = (const float*)d_in[0];
  const float* ea  = (const float*)d_in[1];
  const float* Wt[3]  = {(const float*)d_in[2],  (const float*)d_in[8],  (const float*)d_in[14]};
  const float* Wet[3] = {(const float*)d_in[3],  (const float*)d_in[9],  (const float*)d_in[15]};
  const float* ast[3] = {(const float*)d_in[4],  (const float*)d_in[10], (const float*)d_in[16]};
  const float* adt[3] = {(const float*)d_in[5],  (const float*)d_in[11], (const float*)d_in[17]};
  const float* aet[3] = {(const float*)d_in[6],  (const float*)d_in[12], (const float*)d_in[18]};
  const float* bt[3]  = {(const float*)d_in[7],  (const float*)d_in[13], (const float*)d_in[19]};
  const float* Wc  = (const float*)d_in[20];
  const float* bc  = (const float*)d_in[21];
  const int* ei    = (const int*)d_in[22];
  const int* batch = (const int*)d_in[23];
  int N = in_sizes[0] / 64;
  int E = in_sizes[1] / 147;
  const int* srcp = ei;
  const int* dstp = ei + E;

  char* w = (char*)d_ws;
  size_t off = 0;
  auto carve = [&](size_t bytes)->char*{ char* p = w + off; off += (bytes + 255) & ~(size_t)255; return p; };
  ushort* xh     = (ushort*)carve((size_t)N*512*2);
  ushort* hb     = (ushort*)carve((size_t)N*512*2);
  ushort* xb     = (ushort*)carve((size_t)N*64*2);
  ushort* Wb[3];
  Wb[0] = (ushort*)carve((size_t)512*64*2);
  Wb[1] = (ushort*)carve((size_t)512*512*2);
  Wb[2] = (ushort*)carve((size_t)256*512*2);
  ushort* wfBh   = (ushort*)carve((size_t)32*160*2);
  float*  aEc    = (float*) carve((size_t)E*24*4);
  float*  loopAE = (float*) carve((size_t)N*24*4);
  float*  alphaS = (float*) carve((size_t)N*8*4);
  float*  alphaD = (float*) carve((size_t)N*8*4);
  int*    row_ptr= (int*)   carve((size_t)(N+1)*4);
  int*    epos   = (int*)   carve((size_t)E*4);
  int*    csr_src= (int*)   carve((size_t)E*4);
  int*    bsum   = (int*)   carve((size_t)256*4);
  // zero-region: pooled | cnt | cursor (single memset)
  char*   zbase  = carve(0);
  float*  pooled = (float*) carve((size_t)128*256*4);
  int*    cnt    = (int*)   carve((size_t)N*4);
  int*    cursor = (int*)   carve((size_t)N*4);
  char*   zend   = carve(0);

  hipMemsetAsync(zbase, 0, (size_t)(zend - zbase), stream);

  int nscan = (N+255)/256;
  count_kernel  <<<(E+255)/256, 256, 0, stream>>>(dstp, cnt, E);
  scanA_kernel  <<<nscan, 256, 0, stream>>>(cnt, bsum, N);
  scanB_kernel  <<<1, 256, 0, stream>>>(bsum, nscan);
  scanC_kernel  <<<nscan, 256, 0, stream>>>(cnt, bsum, row_ptr, N);
  scatter_kernel<<<(E+255)/256, 256, 0, stream>>>(srcp, dstp, row_ptr, cursor, epos, csr_src, E);

  wfold_direct_kernel<<<(32*160+255)/256, 256, 0, stream>>>(Wet[0], aet[0], Wet[1], aet[1], Wet[2], aet[2], wfBh);

  conv4_kernel<<<(N*16 + 8192 + 65536 + 32768 + 255)/256, 256, 0, stream>>>(
      x, Wt[0], Wt[1], Wt[2], xb, Wb[0], Wb[1], Wb[2], N*16, 8192, 65536, 32768);

  edge_alpha_mfma_kernel<<<(E+63)/64, 256, 0, stream>>>(ea, wfBh, epos, aEc, E);
  loop_alpha_all_kernel <<<(N+7)/8, 192, 0, stream>>>(aEc, row_ptr, loopAE, N);

  const int HCs[3]  = {512, 512, 256};
  const int CINs[3] = {64, 512, 512};
  int nrow = (N+127)/128;
  for (int l=0; l<3; l++){
    int HC = HCs[l], CIN = CINs[l];
    const ushort* Ain = (l==0) ? xb : hb;
    int NY = HC/128;
    int nwg = nrow * NY;
    if (HC==512) gemm_mfma_kernel<64><<<nwg, 512, 0, stream>>>(Ain, Wb[l], xh, ast[l], adt[l], alphaS, alphaD, N, HC, CIN, NY);
    else         gemm_mfma_kernel<32><<<nwg, 512, 0, stream>>>(Ain, Wb[l], xh, ast[l], adt[l], alphaS, alphaD, N, HC, CIN, NY);
    int ablocks = (N + 7) / 8;   // 4 waves/block, 2 nodes/wave
    if (l==0)
      aggregate_kernel<512,1><<<ablocks, 256, 0, stream>>>(xh, alphaS, alphaD, aEc, loopAE, row_ptr, csr_src, bt[l], hb, N, 0);
    else if (l==1)
      aggregate_kernel<512,1><<<ablocks, 256, 0, stream>>>(xh, alphaS, alphaD, aEc, loopAE, row_ptr, csr_src, bt[l], hb, N, 8);
    else
      aggregate_kernel<256,0><<<ablocks, 256, 0, stream>>>(xh, alphaS, alphaD, aEc, loopAE, row_ptr, csr_src, bt[l], hb, N, 16);
  }
  pool_sum_kernel<<<(N+127)/128, 256, 0, stream>>>(hb, batch, pooled, N);
  final_kernel<<<128, 64, 0, stream>>>(pooled, batch, Wc, bc, (float*)d_out, N);
}